// Round 1
// baseline (597.960 us; speedup 1.0000x reference)
//
#include <hip/hip_runtime.h>
#include <hip/hip_bf16.h>

#define Bb   128
#define Ll   256
#define NIMG 64
#define Dd   1024

typedef __attribute__((ext_vector_type(8))) short bf16x8;
typedef __attribute__((ext_vector_type(4))) float f32x4;

__device__ __forceinline__ float fast_tanh(float x) {
    float xc = fminf(fmaxf(x, -15.f), 15.f);
    float e  = __expf(2.f * xc);
    return (e - 1.f) / (e + 1.f);
}

__device__ __forceinline__ uint pack_bf16x2(float a, float b) {
    __hip_bfloat162 p = __float22bfloat162_rn(make_float2(a, b));
    union { __hip_bfloat162 h; uint u; } c; c.h = p; return c.u;
}

__device__ __forceinline__ float wredmax(float v) {
    #pragma unroll
    for (int o = 32; o; o >>= 1) v = fmaxf(v, __shfl_xor(v, o, 64));
    return v;
}
__device__ __forceinline__ float wredsum(float v) {
    #pragma unroll
    for (int o = 32; o; o >>= 1) v += __shfl_xor(v, o, 64);
    return v;
}

// ---------------- f32 -> bf16 convert (weights preconversion) ----------------
__global__ void cvtk(const float* __restrict__ src, ushort* __restrict__ dst, int n4) {
    int i = blockIdx.x * blockDim.x + threadIdx.x;
    if (i < n4) {
        float4 v = reinterpret_cast<const float4*>(src)[i];
        uint2 o;
        o.x = pack_bf16x2(v.x, v.y);
        o.y = pack_bf16x2(v.z, v.w);
        reinterpret_cast<uint2*>(dst)[i] = o;
    }
}

// ---------------- main GEMM: C = A(f32, MxK) @ W^T(bf16, 1024xK) ----------------
// EPI=0: out[m*1024+n] = C + bias[n]          (q-projections, final output GEMM)
// EPI=1: scores[m] += sum_n tanh(C + q[b][n]) * v[n]   (fused additive-attn scores)
template<int EPI>
__global__ __launch_bounds__(256, 2) void gemm_bt(
    const float* __restrict__ A, const ushort* __restrict__ W,
    const float* __restrict__ qb,   // EPI0: bias[1024]; EPI1: q[B*1024]
    const float* __restrict__ vv,   // EPI1: v[1024]
    float* __restrict__ out,        // EPI0: C (Mx1024); EPI1: scores[M]
    int K, int bshift)
{
    __shared__ char smem[32768];
    char* As = smem;            // [128 rows][128B] bf16, swizzled: byte q^=(row&7)
    char* Ws = smem + 16384;

    const int tid  = threadIdx.x;
    const int lane = tid & 63, wv = tid >> 6, wr = wv >> 1, wc = wv & 1;
    const int m0 = blockIdx.x * 128, n0 = blockIdx.y * 128;
    const int lrow = lane & 15, lk = lane >> 4;

    f32x4 acc[4][4];
    #pragma unroll
    for (int i = 0; i < 4; ++i)
        #pragma unroll
        for (int j = 0; j < 4; ++j) { f32x4 z = {0.f,0.f,0.f,0.f}; acc[i][j] = z; }

    const int tr = tid >> 4;    // A staging: row-in-group
    const int tf = tid & 15;    // float4 index within 64-f32 row
    const int wrow = tid >> 3;  // W staging: row-in-group
    const int wq = tid & 7;     // 16B quadrant within 128B row

    const int nkt = K >> 6;
    for (int kt = 0; kt < nkt; ++kt) {
        // stage A: 128 rows x 64 f32 -> bf16 LDS (swizzled)
        #pragma unroll
        for (int j = 0; j < 8; ++j) {
            int row = j * 16 + tr;
            float4 v = *reinterpret_cast<const float4*>(A + (size_t)(m0 + row) * K + kt * 64 + tf * 4);
            uint2 o;
            o.x = pack_bf16x2(v.x, v.y);
            o.y = pack_bf16x2(v.z, v.w);
            int byte = row * 128 + (((tf >> 1) ^ (row & 7)) << 4) + ((tf & 1) << 3);
            *reinterpret_cast<uint2*>(As + byte) = o;
        }
        // stage W: 128 rows x 64 bf16 -> LDS (swizzled)
        #pragma unroll
        for (int j = 0; j < 4; ++j) {
            int row = j * 32 + wrow;
            uint4 v = *reinterpret_cast<const uint4*>(W + (size_t)(n0 + row) * K + kt * 64 + wq * 8);
            int byte = row * 128 + ((wq ^ (row & 7)) << 4);
            *reinterpret_cast<uint4*>(Ws + byte) = v;
        }
        __syncthreads();
        #pragma unroll
        for (int ks = 0; ks < 2; ++ks) {
            bf16x8 af[4], bfr[4];
            int q = ks * 4 + lk;
            #pragma unroll
            for (int mi = 0; mi < 4; ++mi) {
                int row = wr * 64 + mi * 16 + lrow;
                af[mi] = *reinterpret_cast<const bf16x8*>(As + row * 128 + ((q ^ (row & 7)) << 4));
            }
            #pragma unroll
            for (int ni = 0; ni < 4; ++ni) {
                int row = wc * 64 + ni * 16 + lrow;
                bfr[ni] = *reinterpret_cast<const bf16x8*>(Ws + row * 128 + ((q ^ (row & 7)) << 4));
            }
            #pragma unroll
            for (int mi = 0; mi < 4; ++mi)
                #pragma unroll
                for (int ni = 0; ni < 4; ++ni)
                    acc[mi][ni] = __builtin_amdgcn_mfma_f32_16x16x32_bf16(af[mi], bfr[ni], acc[mi][ni], 0, 0, 0);
        }
        __syncthreads();
    }

    if (EPI == 0) {
        // C/D layout: col = lane&15, row = (lane>>4)*4 + r   [m89 verified]
        #pragma unroll
        for (int mi = 0; mi < 4; ++mi) {
            int mbase = m0 + wr * 64 + mi * 16 + lk * 4;
            #pragma unroll
            for (int ni = 0; ni < 4; ++ni) {
                int n = n0 + wc * 64 + ni * 16 + lrow;
                float bias = qb[n];
                #pragma unroll
                for (int r = 0; r < 4; ++r)
                    out[(size_t)(mbase + r) * 1024 + n] = acc[mi][ni][r] + bias;
            }
        }
    } else {
        #pragma unroll
        for (int mi = 0; mi < 4; ++mi) {
            int mbase = m0 + wr * 64 + mi * 16;
            int b = mbase >> bshift;                 // constant across the fragment
            const float* qrow = qb + (size_t)b * 1024;
            float part[4] = {0.f, 0.f, 0.f, 0.f};
            #pragma unroll
            for (int ni = 0; ni < 4; ++ni) {
                int n = n0 + wc * 64 + ni * 16 + lrow;
                float qn = qrow[n], vn = vv[n];
                #pragma unroll
                for (int r = 0; r < 4; ++r)
                    part[r] += fast_tanh(acc[mi][ni][r] + qn) * vn;
            }
            #pragma unroll
            for (int off = 1; off < 16; off <<= 1)
                #pragma unroll
                for (int r = 0; r < 4; ++r)
                    part[r] += __shfl_xor(part[r], off, 64);
            if (lrow == 0) {
                #pragma unroll
                for (int r = 0; r < 4; ++r)
                    atomicAdd(&out[mbase + lk * 4 + r], part[r]);
            }
        }
    }
}

// ---------------- softmax + context, image branches (no mask, 64 regions) ----------------
__global__ void softmax_ctx_img(const float* __restrict__ iof, const float* __restrict__ ipf,
                                const float* __restrict__ sc_io, const float* __restrict__ sc_ip,
                                float* __restrict__ combined)
{
    int b = blockIdx.x, br = blockIdx.y >> 2, chunk = blockIdx.y & 3;
    const float* A  = br ? ipf : iof;
    const float* sc = br ? sc_ip : sc_io;
    __shared__ float dist[64];
    int tid = threadIdx.x;
    if (tid < 64) {
        float s  = sc[b * 64 + tid];
        float mx = wredmax(s);
        float e  = __expf(s - mx);
        float sm = wredsum(e);
        dist[tid] = e / sm;
    }
    __syncthreads();
    int d = chunk * 256 + tid;
    float acc = 0.f;
    #pragma unroll 4
    for (int n = 0; n < 64; ++n)
        acc += dist[n] * A[(size_t)(b * 64 + n) * 1024 + d];
    combined[(size_t)b * 4096 + br * 1024 + d] = acc;
}

// ---------------- masked softmax + context, text branches (both fused) ----------------
__global__ void softmax_ctx_text(const float* __restrict__ tf,
                                 const float* __restrict__ sc_to, const float* __restrict__ sc_tp,
                                 const float* __restrict__ mask, float* __restrict__ combined)
{
    int b = blockIdx.x, chunk = blockIdx.y;
    __shared__ float d3[256], d4[256], red[8];
    int tid = threadIdx.x, lane = tid & 63, wv = tid >> 6;
    float s3 = sc_to[b * 256 + tid], s4 = sc_tp[b * 256 + tid], m = mask[b * 256 + tid];
    float m3 = wredmax(s3), m4 = wredmax(s4);
    if (lane == 0) { red[wv] = m3; red[4 + wv] = m4; }
    __syncthreads();
    m3 = fmaxf(fmaxf(red[0], red[1]), fmaxf(red[2], red[3]));
    m4 = fmaxf(fmaxf(red[4], red[5]), fmaxf(red[6], red[7]));
    // softmax then mask then renorm == masked softmax (exact)
    float e3 = __expf(s3 - m3) * m, e4 = __expf(s4 - m4) * m;
    float t3 = wredsum(e3), t4 = wredsum(e4);
    __syncthreads();
    if (lane == 0) { red[wv] = t3; red[4 + wv] = t4; }
    __syncthreads();
    t3 = red[0] + red[1] + red[2] + red[3];
    t4 = red[4] + red[5] + red[6] + red[7];
    d3[tid] = e3 / t3; d4[tid] = e4 / t4;
    __syncthreads();
    int d = chunk * 256 + tid;
    float a3 = 0.f, a4 = 0.f;
    #pragma unroll 4
    for (int l = 0; l < 256; ++l) {
        float t = tf[(size_t)(b * 256 + l) * 1024 + d];
        a3 += d3[l] * t; a4 += d4[l] * t;
    }
    combined[(size_t)b * 4096 + 2048 + d] = a3;
    combined[(size_t)b * 4096 + 3072 + d] = a4;
}

extern "C" void kernel_launch(void* const* d_in, const int* in_sizes, int n_in,
                              void* d_out, int out_size, void* d_ws, size_t ws_size,
                              hipStream_t stream) {
    const float* text_feat        = (const float*)d_in[0];
    const float* text_feats       = (const float*)d_in[1];
    const float* img_object_feat  = (const float*)d_in[2];
    const float* img_object_feats = (const float*)d_in[3];
    const float* img_place_feat   = (const float*)d_in[4];
    const float* img_place_feats  = (const float*)d_in[5];
    const float* src_mask         = (const float*)d_in[6];
    const float* v_to  = (const float*)d_in[7];
    const float* v_tp  = (const float*)d_in[8];
    const float* v_io  = (const float*)d_in[9];
    const float* v_ip  = (const float*)d_in[10];
    const float* W_t2o = (const float*)d_in[11];
    const float* W_t2p = (const float*)d_in[12];
    const float* W_o2t = (const float*)d_in[13];
    const float* W_p2t = (const float*)d_in[14];
    const float* W_oo  = (const float*)d_in[15];
    const float* b_oo  = (const float*)d_in[16];
    const float* W_pp  = (const float*)d_in[17];
    const float* b_pp  = (const float*)d_in[18];
    const float* W_tot = (const float*)d_in[19];
    const float* b_tot = (const float*)d_in[20];
    const float* W_tpt = (const float*)d_in[21];
    const float* b_tpt = (const float*)d_in[22];
    const float* W_out = (const float*)d_in[23];
    const float* b_out = (const float*)d_in[24];

    char* ws = (char*)d_ws;
    const size_t MB = 1024 * 1024;
    ushort* wb_t2o = (ushort*)ws;
    ushort* wb_t2p = wb_t2o + 1 * MB;
    ushort* wb_o2t = wb_t2o + 2 * MB;
    ushort* wb_p2t = wb_t2o + 3 * MB;
    ushort* wb_oo  = wb_t2o + 4 * MB;
    ushort* wb_pp  = wb_t2o + 5 * MB;
    ushort* wb_tot = wb_t2o + 6 * MB;
    ushort* wb_tpt = wb_t2o + 7 * MB;
    ushort* wb_out = wb_t2o + 8 * MB;   // 4M elements
    float* q_tot = (float*)(ws + 24 * MB);
    float* q_tpt = q_tot + 131072;
    float* q_oo  = q_tot + 2 * 131072;
    float* q_pp  = q_tot + 3 * 131072;
    float* sc_io = q_tot + 4 * 131072;  // 8192
    float* sc_ip = sc_io + 8192;
    float* sc_to = sc_ip + 8192;        // 32768
    float* sc_tp = sc_to + 32768;
    float* combined = sc_tp + 32768;    // 128*4096

    // 1) preconvert all weight matrices to bf16
    cvtk<<<1024, 256, 0, stream>>>(W_t2o, wb_t2o, 262144);
    cvtk<<<1024, 256, 0, stream>>>(W_t2p, wb_t2p, 262144);
    cvtk<<<1024, 256, 0, stream>>>(W_o2t, wb_o2t, 262144);
    cvtk<<<1024, 256, 0, stream>>>(W_p2t, wb_p2t, 262144);
    cvtk<<<1024, 256, 0, stream>>>(W_oo,  wb_oo,  262144);
    cvtk<<<1024, 256, 0, stream>>>(W_pp,  wb_pp,  262144);
    cvtk<<<1024, 256, 0, stream>>>(W_tot, wb_tot, 262144);
    cvtk<<<1024, 256, 0, stream>>>(W_tpt, wb_tpt, 262144);
    cvtk<<<4096, 256, 0, stream>>>(W_out, wb_out, 1048576);

    // 2) zero score accumulators (atomicAdd targets) — every call (ws is poisoned)
    hipMemsetAsync(sc_io, 0, (8192 * 2 + 32768 * 2) * sizeof(float), stream);

    // 3) q projections: q = x @ W^T + b  (M=128)
    gemm_bt<0><<<dim3(1, 8), 256, 0, stream>>>(text_feat,       wb_tot, b_tot, nullptr, q_tot, 1024, 0);
    gemm_bt<0><<<dim3(1, 8), 256, 0, stream>>>(text_feat,       wb_tpt, b_tpt, nullptr, q_tpt, 1024, 0);
    gemm_bt<0><<<dim3(1, 8), 256, 0, stream>>>(img_object_feat, wb_oo,  b_oo,  nullptr, q_oo,  1024, 0);
    gemm_bt<0><<<dim3(1, 8), 256, 0, stream>>>(img_place_feat,  wb_pp,  b_pp,  nullptr, q_pp,  1024, 0);

    // 4) fused score GEMMs: scores[m] = sum_n tanh(A@W^T + q[b]) * v
    gemm_bt<1><<<dim3(64, 8),  256, 0, stream>>>(img_object_feats, wb_o2t, q_tot, v_to, sc_io, 1024, 6);
    gemm_bt<1><<<dim3(64, 8),  256, 0, stream>>>(img_place_feats,  wb_p2t, q_tpt, v_tp, sc_ip, 1024, 6);
    gemm_bt<1><<<dim3(256, 8), 256, 0, stream>>>(text_feats,       wb_t2o, q_oo,  v_io, sc_to, 1024, 8);
    gemm_bt<1><<<dim3(256, 8), 256, 0, stream>>>(text_feats,       wb_t2p, q_pp,  v_ip, sc_tp, 1024, 8);

    // 5) softmax + weighted-sum contexts -> combined[B][4096]
    softmax_ctx_img<<<dim3(128, 8), 256, 0, stream>>>(img_object_feats, img_place_feats, sc_io, sc_ip, combined);
    softmax_ctx_text<<<dim3(128, 4), 256, 0, stream>>>(text_feats, sc_to, sc_tp, src_mask, combined);

    // 6) output: out = combined @ W_out^T + b_out  (M=128, K=4096)
    gemm_bt<0><<<dim3(1, 8), 256, 0, stream>>>(combined, wb_out, b_out, nullptr, (float*)d_out, 4096, 0);
}

// Round 2
// 401.739 us; speedup vs baseline: 1.4884x; 1.4884x over previous
//
#include <hip/hip_runtime.h>
#include <hip/hip_bf16.h>

typedef __attribute__((ext_vector_type(8))) short bf16x8;
typedef __attribute__((ext_vector_type(4))) float f32x4;

__device__ __forceinline__ uint pack_bf16x2(float a, float b) {
    __hip_bfloat162 p = __float22bfloat162_rn(make_float2(a, b));
    union { __hip_bfloat162 h; uint u; } c; c.h = p; return c.u;
}
__device__ __forceinline__ float bfu(ushort u) { return __uint_as_float(((uint)u) << 16); }

__device__ __forceinline__ float fast_tanh(float x) {
    // tanh(x) = 1 - 2/(e^{2x}+1); inf-safe at both ends
    float e = __expf(2.f * x);
    return 1.f - 2.f * __builtin_amdgcn_rcpf(e + 1.f);
}

__device__ __forceinline__ float wredmax(float v) {
    #pragma unroll
    for (int o = 32; o; o >>= 1) v = fmaxf(v, __shfl_xor(v, o, 64));
    return v;
}
__device__ __forceinline__ float wredsum(float v) {
    #pragma unroll
    for (int o = 32; o; o >>= 1) v += __shfl_xor(v, o, 64);
    return v;
}

__device__ __forceinline__ void gload16(const void* g, void* l) {
    __builtin_amdgcn_global_load_lds(
        (const __attribute__((address_space(1))) void*)g,
        (__attribute__((address_space(3))) void*)l, 16, 0, 0);
}

// ---------------- batched f32 -> bf16 conversion ----------------
struct CvtTab {
    const float* src[16];
    ushort* dst[16];
    unsigned cum[17];   // cumulative float4 counts
};

__global__ void cvt_all(CvtTab t, unsigned total4) {
    unsigned stride = gridDim.x * blockDim.x;
    for (unsigned i = blockIdx.x * blockDim.x + threadIdx.x; i < total4; i += stride) {
        int j = 0;
        while (i >= t.cum[j + 1]) ++j;
        unsigned off = i - t.cum[j];
        float4 v = reinterpret_cast<const float4*>(t.src[j])[off];
        uint2 o;
        o.x = pack_bf16x2(v.x, v.y);
        o.y = pack_bf16x2(v.z, v.w);
        reinterpret_cast<uint2*>(t.dst[j])[off] = o;
    }
}

// ---------------- GEMM: C = A(bf16, MxK) @ W^T(bf16, 1024xK) ----------------
// EPI 0: out1[m*1024+n] = C + qb1[n]
// EPI 1: scores: out[m] += sum_n tanh(C + q[b][n]) * v[n]   (atomicAdd)
// EPI 2: atomicAdd(out1[m*1024+n], C + (z==0 ? qb1[n] : 0))  (split-K)
// MODE 0: plain. MODE 1: dual-W (W1,W2 share A; both epilogues).
// MODE 2: branch select by blockIdx.x>>6 (A/W/qb/v/out from slot 2 when br=1).
template<int EPI, int MODE>
__global__ __launch_bounds__(256, 2) void gemm_bt(
    const ushort* A, const ushort* A2,
    const ushort* W1, const ushort* W2,
    const float* qb1, const float* qb2,
    const float* v1, const float* v2,
    float* out1, float* out2,
    int K, int kchunk, int bshift)
{
    __shared__ char smem[(MODE == 1) ? 49152 : 32768];
    char* As  = smem;
    char* Ws1 = smem + 16384;
    char* Ws2 = smem + 32768;   // MODE 1 only

    const int tid  = threadIdx.x;
    const int lane = tid & 63, wv = tid >> 6, wr = wv >> 1, wc = wv & 1;
    const int lrow = lane & 15, lk = lane >> 4;

    int m0;
    if (MODE == 2) {
        int br = blockIdx.x >> 6;
        m0 = (blockIdx.x & 63) << 7;
        if (br) { A = A2; W1 = W2; qb1 = qb2; v1 = v2; out1 = out2; }
    } else {
        m0 = blockIdx.x << 7;
    }
    const int n0 = blockIdx.y << 7;
    const int nkt = kchunk >> 6;
    const int ktbase = blockIdx.z * nkt;

    f32x4 acc1[4][4], acc2[4][4];
    #pragma unroll
    for (int i = 0; i < 4; ++i)
        #pragma unroll
        for (int j = 0; j < 4; ++j) {
            f32x4 z = {0.f, 0.f, 0.f, 0.f};
            acc1[i][j] = z;
            if (MODE == 1) acc2[i][j] = z;
        }

    // staging geometry: per call j, wave wv covers rows j*32 + wv*8 .. +8,
    // lane's 16B chunk lands at LDS byte j*4096 + tid*16 == row*128 + c*16
    // with c = tid&7; source chunk g = c ^ (row&7)  (same XOR as ds_read).
    const int srow = tid >> 3;                       // 0..31
    const int g    = (tid & 7) ^ (srow & 7);
    const ushort* pA  = A  + (size_t)(m0 + srow) * K + ktbase * 64 + g * 8;
    const ushort* pW1 = W1 + (size_t)(n0 + srow) * K + ktbase * 64 + g * 8;
    const ushort* pW2 = (MODE == 1) ? (W2 + (size_t)(n0 + srow) * K + ktbase * 64 + g * 8) : nullptr;
    char* ldsA  = As  + wv * 1024;
    char* ldsW1 = Ws1 + wv * 1024;
    char* ldsW2 = Ws2 + wv * 1024;

    for (int t = 0; t < nkt; ++t) {
        #pragma unroll
        for (int j = 0; j < 4; ++j)
            gload16(pA + (size_t)j * 32 * K, ldsA + j * 4096);
        #pragma unroll
        for (int j = 0; j < 4; ++j)
            gload16(pW1 + (size_t)j * 32 * K, ldsW1 + j * 4096);
        if (MODE == 1) {
            #pragma unroll
            for (int j = 0; j < 4; ++j)
                gload16(pW2 + (size_t)j * 32 * K, ldsW2 + j * 4096);
        }
        pA += 64; pW1 += 64; if (MODE == 1) pW2 += 64;
        __syncthreads();

        #pragma unroll
        for (int ks = 0; ks < 2; ++ks) {
            bf16x8 af[4], b1[4], b2[4];
            const int q = ks * 4 + lk;
            #pragma unroll
            for (int mi = 0; mi < 4; ++mi) {
                int row = wr * 64 + mi * 16 + lrow;
                af[mi] = *(const bf16x8*)(As + row * 128 + ((q ^ (row & 7)) << 4));
            }
            #pragma unroll
            for (int ni = 0; ni < 4; ++ni) {
                int row = wc * 64 + ni * 16 + lrow;
                b1[ni] = *(const bf16x8*)(Ws1 + row * 128 + ((q ^ (row & 7)) << 4));
                if (MODE == 1)
                    b2[ni] = *(const bf16x8*)(Ws2 + row * 128 + ((q ^ (row & 7)) << 4));
            }
            #pragma unroll
            for (int mi = 0; mi < 4; ++mi)
                #pragma unroll
                for (int ni = 0; ni < 4; ++ni) {
                    acc1[mi][ni] = __builtin_amdgcn_mfma_f32_16x16x32_bf16(af[mi], b1[ni], acc1[mi][ni], 0, 0, 0);
                    if (MODE == 1)
                        acc2[mi][ni] = __builtin_amdgcn_mfma_f32_16x16x32_bf16(af[mi], b2[ni], acc2[mi][ni], 0, 0, 0);
                }
        }
        __syncthreads();
    }

    // C/D layout: col(n) = lane&15, row(m) = (lane>>4)*4 + r   [m89 verified]
    if (EPI == 0 || EPI == 2) {
        #pragma unroll
        for (int mi = 0; mi < 4; ++mi) {
            int mrow0 = m0 + wr * 64 + mi * 16 + lk * 4;
            #pragma unroll
            for (int ni = 0; ni < 4; ++ni) {
                int n = n0 + wc * 64 + ni * 16 + lrow;
                float bias = (EPI == 0 || blockIdx.z == 0) ? qb1[n] : 0.f;
                #pragma unroll
                for (int r = 0; r < 4; ++r) {
                    if (EPI == 0)
                        out1[(size_t)(mrow0 + r) * 1024 + n] = acc1[mi][ni][r] + bias;
                    else
                        atomicAdd(&out1[(size_t)(mrow0 + r) * 1024 + n], acc1[mi][ni][r] + bias);
                }
            }
        }
    } else {
        auto scoreEpi = [&](f32x4 (&acc)[4][4], const float* qb, const float* vvp, float* outp) {
            #pragma unroll
            for (int mi = 0; mi < 4; ++mi) {
                int mbase = m0 + wr * 64 + mi * 16;
                int b = mbase >> bshift;
                const float* qrow = qb + (size_t)b * 1024;
                float part[4] = {0.f, 0.f, 0.f, 0.f};
                #pragma unroll
                for (int ni = 0; ni < 4; ++ni) {
                    int n = n0 + wc * 64 + ni * 16 + lrow;
                    float qn = qrow[n], vn = vvp[n];
                    #pragma unroll
                    for (int r = 0; r < 4; ++r)
                        part[r] += fast_tanh(acc[mi][ni][r] + qn) * vn;
                }
                #pragma unroll
                for (int off = 1; off < 16; off <<= 1)
                    #pragma unroll
                    for (int r = 0; r < 4; ++r)
                        part[r] += __shfl_xor(part[r], off, 64);
                if (lrow == 0) {
                    #pragma unroll
                    for (int r = 0; r < 4; ++r)
                        atomicAdd(&outp[mbase + lk * 4 + r], part[r]);
                }
            }
        };
        scoreEpi(acc1, qb1, v1, out1);
        if (MODE == 1) scoreEpi(acc2, qb2, v2, out2);
    }
}

// ---------------- softmax + context, image branches ----------------
__global__ void softmax_ctx_img(const ushort* __restrict__ iof, const ushort* __restrict__ ipf,
                                const float* __restrict__ sc_io, const float* __restrict__ sc_ip,
                                ushort* __restrict__ combined)
{
    int b = blockIdx.x, br = blockIdx.y;
    const ushort* A  = br ? ipf : iof;
    const float* sc  = br ? sc_ip : sc_io;
    __shared__ float dist[64];
    int tid = threadIdx.x;
    if (tid < 64) {
        float s  = sc[b * 64 + tid];
        float mx = wredmax(s);
        float e  = __expf(s - mx);
        float sm = wredsum(e);
        dist[tid] = e / sm;
    }
    __syncthreads();
    int d0 = tid * 4;
    float a0 = 0, a1 = 0, a2 = 0, a3 = 0;
    const ushort* base = A + (size_t)b * 64 * 1024 + d0;
    #pragma unroll 4
    for (int n = 0; n < 64; ++n) {
        float w = dist[n];
        ushort4 t = *(const ushort4*)(base + (size_t)n * 1024);
        a0 += w * bfu(t.x); a1 += w * bfu(t.y); a2 += w * bfu(t.z); a3 += w * bfu(t.w);
    }
    uint2 o;
    o.x = pack_bf16x2(a0, a1);
    o.y = pack_bf16x2(a2, a3);
    *(uint2*)(combined + (size_t)b * 4096 + br * 1024 + d0) = o;
}

// ---------------- masked softmax + context, text branches ----------------
__global__ void softmax_ctx_text(const ushort* __restrict__ tf,
                                 const float* __restrict__ sc_to, const float* __restrict__ sc_tp,
                                 const float* __restrict__ mask, ushort* __restrict__ combined)
{
    int b = blockIdx.x;
    __shared__ float d3[256], d4[256], red[8];
    int tid = threadIdx.x, lane = tid & 63, wv = tid >> 6;
    float s3 = sc_to[b * 256 + tid], s4 = sc_tp[b * 256 + tid], m = mask[b * 256 + tid];
    float m3 = wredmax(s3), m4 = wredmax(s4);
    if (lane == 0) { red[wv] = m3; red[4 + wv] = m4; }
    __syncthreads();
    m3 = fmaxf(fmaxf(red[0], red[1]), fmaxf(red[2], red[3]));
    m4 = fmaxf(fmaxf(red[4], red[5]), fmaxf(red[6], red[7]));
    float e3 = __expf(s3 - m3) * m, e4 = __expf(s4 - m4) * m;
    float t3 = wredsum(e3), t4 = wredsum(e4);
    __syncthreads();
    if (lane == 0) { red[wv] = t3; red[4 + wv] = t4; }
    __syncthreads();
    t3 = red[0] + red[1] + red[2] + red[3];
    t4 = red[4] + red[5] + red[6] + red[7];
    d3[tid] = e3 / t3; d4[tid] = e4 / t4;
    __syncthreads();
    int d0 = tid * 4;
    float a0 = 0, a1 = 0, a2 = 0, a3 = 0, c0 = 0, c1 = 0, c2 = 0, c3 = 0;
    const ushort* base = tf + (size_t)b * 256 * 1024 + d0;
    #pragma unroll 4
    for (int l = 0; l < 256; ++l) {
        float w3 = d3[l], w4 = d4[l];
        ushort4 t = *(const ushort4*)(base + (size_t)l * 1024);
        float f0 = bfu(t.x), f1 = bfu(t.y), f2 = bfu(t.z), f3 = bfu(t.w);
        a0 += w3 * f0; a1 += w3 * f1; a2 += w3 * f2; a3 += w3 * f3;
        c0 += w4 * f0; c1 += w4 * f1; c2 += w4 * f2; c3 += w4 * f3;
    }
    uint2 o;
    o.x = pack_bf16x2(a0, a1); o.y = pack_bf16x2(a2, a3);
    *(uint2*)(combined + (size_t)b * 4096 + 2048 + d0) = o;
    o.x = pack_bf16x2(c0, c1); o.y = pack_bf16x2(c2, c3);
    *(uint2*)(combined + (size_t)b * 4096 + 3072 + d0) = o;
}

extern "C" void kernel_launch(void* const* d_in, const int* in_sizes, int n_in,
                              void* d_out, int out_size, void* d_ws, size_t ws_size,
                              hipStream_t stream) {
    const float* text_feat        = (const float*)d_in[0];
    const float* text_feats       = (const float*)d_in[1];
    const float* img_object_feat  = (const float*)d_in[2];
    const float* img_object_feats = (const float*)d_in[3];
    const float* img_place_feat   = (const float*)d_in[4];
    const float* img_place_feats  = (const float*)d_in[5];
    const float* src_mask         = (const float*)d_in[6];
    const float* v_to  = (const float*)d_in[7];
    const float* v_tp  = (const float*)d_in[8];
    const float* v_io  = (const float*)d_in[9];
    const float* v_ip  = (const float*)d_in[10];
    const float* Wsrc[9] = {
        (const float*)d_in[11],  // W_t2o
        (const float*)d_in[12],  // W_t2p
        (const float*)d_in[13],  // W_o2t
        (const float*)d_in[14],  // W_p2t
        (const float*)d_in[15],  // W_oo
        (const float*)d_in[17],  // W_pp
        (const float*)d_in[19],  // W_tot
        (const float*)d_in[21],  // W_tpt
        (const float*)d_in[23],  // W_out
    };
    const float* b_oo  = (const float*)d_in[16];
    const float* b_pp  = (const float*)d_in[18];
    const float* b_tot = (const float*)d_in[20];
    const float* b_tpt = (const float*)d_in[22];
    const float* b_out = (const float*)d_in[24];

    // ---- workspace layout ----
    char* p = (char*)d_ws;
    auto alloc = [&](size_t bytes) { char* r = p; p += (bytes + 255) & ~(size_t)255; return r; };
    ushort* wb[9];
    for (int i = 0; i < 8; ++i) wb[i] = (ushort*)alloc((size_t)1024 * 1024 * 2);
    wb[8] = (ushort*)alloc((size_t)1024 * 4096 * 2);           // W_out bf16
    ushort* tf_bf   = (ushort*)alloc((size_t)32768 * 1024 * 2);
    ushort* iof_bf  = (ushort*)alloc((size_t)8192 * 1024 * 2);
    ushort* ipf_bf  = (ushort*)alloc((size_t)8192 * 1024 * 2);
    ushort* tfq_bf  = (ushort*)alloc((size_t)128 * 1024 * 2);
    ushort* iofq_bf = (ushort*)alloc((size_t)128 * 1024 * 2);
    ushort* ipfq_bf = (ushort*)alloc((size_t)128 * 1024 * 2);
    float* q_tot = (float*)alloc((size_t)128 * 1024 * 4);
    float* q_tpt = (float*)alloc((size_t)128 * 1024 * 4);
    float* q_oo  = (float*)alloc((size_t)128 * 1024 * 4);
    float* q_pp  = (float*)alloc((size_t)128 * 1024 * 4);
    float* scores = (float*)alloc((size_t)(8192 * 2 + 32768 * 2) * 4);
    float* sc_io = scores, *sc_ip = scores + 8192, *sc_to = scores + 16384, *sc_tp = scores + 49152;
    ushort* comb_bf = (ushort*)alloc((size_t)128 * 4096 * 2);

    // ---- 1) batched f32->bf16 conversion ----
    CvtTab tab;
    unsigned n4[15];
    const float* srcs[15];
    ushort* dsts[15];
    for (int i = 0; i < 8; ++i) { srcs[i] = Wsrc[i]; dsts[i] = wb[i]; n4[i] = 262144; }
    srcs[8]  = Wsrc[8];          dsts[8]  = wb[8];   n4[8]  = 1048576;
    srcs[9]  = text_feats;       dsts[9]  = tf_bf;   n4[9]  = 8388608;
    srcs[10] = img_object_feats; dsts[10] = iof_bf;  n4[10] = 2097152;
    srcs[11] = img_place_feats;  dsts[11] = ipf_bf;  n4[11] = 2097152;
    srcs[12] = text_feat;        dsts[12] = tfq_bf;  n4[12] = 32768;
    srcs[13] = img_object_feat;  dsts[13] = iofq_bf; n4[13] = 32768;
    srcs[14] = img_place_feat;   dsts[14] = ipfq_bf; n4[14] = 32768;
    unsigned cum = 0;
    for (int i = 0; i < 15; ++i) {
        tab.src[i] = srcs[i]; tab.dst[i] = dsts[i]; tab.cum[i] = cum; cum += n4[i];
    }
    for (int i = 15; i < 16; ++i) { tab.src[i] = nullptr; tab.dst[i] = nullptr; tab.cum[i] = cum; }
    tab.cum[16] = cum;
    cvt_all<<<4096, 256, 0, stream>>>(tab, cum);

    // ---- 2) zero atomic targets ----
    hipMemsetAsync(scores, 0, (size_t)(8192 * 2 + 32768 * 2) * 4, stream);
    hipMemsetAsync(d_out, 0, (size_t)128 * 1024 * 4, stream);

    // ---- 3) q projections: q = x @ W^T + b ----
    gemm_bt<0, 0><<<dim3(1, 8, 1), 256, 0, stream>>>(tfq_bf, nullptr, wb[6], nullptr,
        b_tot, nullptr, nullptr, nullptr, q_tot, nullptr, 1024, 1024, 0);
    gemm_bt<0, 0><<<dim3(1, 8, 1), 256, 0, stream>>>(tfq_bf, nullptr, wb[7], nullptr,
        b_tpt, nullptr, nullptr, nullptr, q_tpt, nullptr, 1024, 1024, 0);
    gemm_bt<0, 0><<<dim3(1, 8, 1), 256, 0, stream>>>(iofq_bf, nullptr, wb[4], nullptr,
        b_oo, nullptr, nullptr, nullptr, q_oo, nullptr, 1024, 1024, 0);
    gemm_bt<0, 0><<<dim3(1, 8, 1), 256, 0, stream>>>(ipfq_bf, nullptr, wb[5], nullptr,
        b_pp, nullptr, nullptr, nullptr, q_pp, nullptr, 1024, 1024, 0);

    // ---- 4) score GEMMs ----
    // img branches (block-selected): obj -> sc_io, place -> sc_ip
    gemm_bt<1, 2><<<dim3(128, 8, 1), 256, 0, stream>>>(iof_bf, ipf_bf, wb[2], wb[3],
        q_tot, q_tpt, v_to, v_tp, sc_io, sc_ip, 1024, 1024, 6);
    // text dual-W: one A-pass, both W_t2o/W_t2p
    gemm_bt<1, 1><<<dim3(256, 8, 1), 256, 0, stream>>>(tf_bf, nullptr, wb[0], wb[1],
        q_oo, q_pp, v_io, v_ip, sc_to, sc_tp, 1024, 1024, 8);

    // ---- 5) softmax + context -> combined (bf16) ----
    softmax_ctx_img<<<dim3(128, 2), 256, 0, stream>>>(iof_bf, ipf_bf, sc_io, sc_ip, comb_bf);
    softmax_ctx_text<<<dim3(128), 256, 0, stream>>>(tf_bf, sc_to, sc_tp, src_mask, comb_bf);

    // ---- 6) out = combined @ W_out^T + b_out (split-K=4, atomic) ----
    gemm_bt<2, 0><<<dim3(1, 8, 4), 256, 0, stream>>>(comb_bf, nullptr, wb[8], nullptr,
        b_out, nullptr, nullptr, nullptr, (float*)d_out, nullptr, 4096, 1024, 0);
}

// Round 3
// 310.977 us; speedup vs baseline: 1.9228x; 1.2919x over previous
//
#include <hip/hip_runtime.h>
#include <hip/hip_bf16.h>

typedef __attribute__((ext_vector_type(8))) short bf16x8;
typedef __attribute__((ext_vector_type(4))) float f32x4;

__device__ __forceinline__ uint pack_bf16x2(float a, float b) {
    __hip_bfloat162 p = __float22bfloat162_rn(make_float2(a, b));
    union { __hip_bfloat162 h; uint u; } c; c.h = p; return c.u;
}
__device__ __forceinline__ float bfu(ushort u) { return __uint_as_float(((uint)u) << 16); }

__device__ __forceinline__ float fast_tanh(float x) {
    float e = __expf(2.f * x);
    return 1.f - 2.f * __builtin_amdgcn_rcpf(e + 1.f);
}

__device__ __forceinline__ float wredmax(float v) {
    #pragma unroll
    for (int o = 32; o; o >>= 1) v = fmaxf(v, __shfl_xor(v, o, 64));
    return v;
}
__device__ __forceinline__ float wredsum(float v) {
    #pragma unroll
    for (int o = 32; o; o >>= 1) v += __shfl_xor(v, o, 64);
    return v;
}

__device__ __forceinline__ void gload16(const void* g, void* l) {
    __builtin_amdgcn_global_load_lds(
        (const __attribute__((address_space(1))) void*)g,
        (__attribute__((address_space(3))) void*)l, 16, 0, 0);
}

// ---------------- batched f32 -> bf16 conversion ----------------
struct CvtTab {
    const float* src[16];
    ushort* dst[16];
    unsigned cum[17];
};

__global__ void cvt_all(CvtTab t, unsigned total4) {
    unsigned stride = gridDim.x * blockDim.x;
    for (unsigned i = blockIdx.x * blockDim.x + threadIdx.x; i < total4; i += stride) {
        int j = 0;
        while (i >= t.cum[j + 1]) ++j;
        unsigned off = i - t.cum[j];
        float4 v = reinterpret_cast<const float4*>(t.src[j])[off];
        uint2 o;
        o.x = pack_bf16x2(v.x, v.y);
        o.y = pack_bf16x2(v.z, v.w);
        reinterpret_cast<uint2*>(t.dst[j])[off] = o;
    }
}

// ============ deep-pipelined score GEMM: 512 thr, 256x256 tile, dbuf 128KB LDS ============
// Tile: A rows m0..m0+255 (K=1024), N-concat = [Wa tile rows na..na+127 | Wb rows nb..nb+127].
// 8 waves: wr=wv>>2 (M-half of 128), wc=wv&3 (64-col group); per-wave 128x64, acc[8][4].
// Epilogue: scores[m] += sum_n tanh(C + q[b][n]) * v[n]  (atomicAdd, per side).
struct PArgs {
    const ushort* A[2];
    const ushort* Wa[2];
    const ushort* Wb[2];
    const float* qa[2];
    const float* qb[2];
    const float* va[2];
    const float* vb[2];
    float* oa[2];
    float* ob[2];
};

__global__ __launch_bounds__(512, 2) void gemm_pipe(PArgs P, int nmul, int nbadd,
                                                    int bshift, int brshift)
{
    extern __shared__ char smem[];
    char* A0 = smem;
    char* A1 = smem + 32768;
    char* W0 = smem + 65536;
    char* W1 = smem + 98304;

    const int tid = threadIdx.x;
    const int lane = tid & 63, wv = tid >> 6;
    const int wr = wv >> 2, wc = wv & 3;
    const int lrow = lane & 15, lk = lane >> 4;

    const int br = blockIdx.x >> brshift;
    const int m0 = (blockIdx.x & ((1 << brshift) - 1)) << 8;
    const int na = blockIdx.y * nmul;
    const int nb = na + nbadd;

    const ushort* A  = P.A[br];
    const ushort* Wa = P.Wa[br];
    const ushort* Wb = P.Wb[br];

    // staging: per round, 512 thr x 16B = 8KB = 64 rows x 128B (linear LDS dest;
    // source chunk pre-swizzled with the same XOR used on ds_read — rule 21)
    const int srow = tid >> 3;
    const int g = (tid & 7) ^ (srow & 7);
    const int sdst = tid * 16;
    const ushort* pA  = A  + (size_t)(m0 + srow) * 1024 + g * 8;
    const ushort* pWa = Wa + (size_t)(na + srow) * 1024 + g * 8;
    const ushort* pWb = Wb + (size_t)(nb + srow) * 1024 + g * 8;

    f32x4 acc[8][4];
    #pragma unroll
    for (int i = 0; i < 8; ++i)
        #pragma unroll
        for (int j = 0; j < 4; ++j) { f32x4 z = {0.f,0.f,0.f,0.f}; acc[i][j] = z; }

    auto stA = [&](int tt, char* dst, int jh) {
        #pragma unroll
        for (int j = jh * 2; j < jh * 2 + 2; ++j)
            gload16(pA + (size_t)j * 65536 + (size_t)tt * 64, dst + j * 8192 + sdst);
    };
    auto stW = [&](int tt, char* dst, int jh) {
        if (jh == 0) {
            gload16(pWa + (size_t)tt * 64,         dst + sdst);
            gload16(pWa + 65536 + (size_t)tt * 64, dst + 8192 + sdst);
        } else {
            gload16(pWb + (size_t)tt * 64,         dst + 16384 + sdst);
            gload16(pWb + 65536 + (size_t)tt * 64, dst + 24576 + sdst);
        }
    };
    auto rdA = [&](char* buf, int ks, int mi) -> bf16x8 {
        int row = wr * 128 + mi * 16 + lrow;
        return *(const bf16x8*)(buf + row * 128 + (((ks * 4 + lk) ^ (row & 7)) << 4));
    };
    auto rdB = [&](char* buf, int ks, int ni) -> bf16x8 {
        int row = wc * 64 + ni * 16 + lrow;
        return *(const bf16x8*)(buf + row * 128 + (((ks * 4 + lk) ^ (row & 7)) << 4));
    };

    // prologue: stage tile 0
    stA(0, A0, 0); stA(0, A0, 1); stW(0, W0, 0); stW(0, W0, 1);
    asm volatile("s_waitcnt vmcnt(0)" ::: "memory");
    __builtin_amdgcn_s_barrier();

    auto body = [&](int t, char* cA, char* cW, char* nA, char* nW, bool pf) {
        bf16x8 af[4], bfr[4];
        // ---- phase 0: ks=0, mi 0-3 (stage A half 0 of t+1)
        if (pf) stA(t + 1, nA, 0);
        #pragma unroll
        for (int ni = 0; ni < 4; ++ni) bfr[ni] = rdB(cW, 0, ni);
        #pragma unroll
        for (int mi = 0; mi < 4; ++mi) af[mi] = rdA(cA, 0, mi);
        __builtin_amdgcn_s_setprio(1);
        #pragma unroll
        for (int mi = 0; mi < 4; ++mi)
            #pragma unroll
            for (int ni = 0; ni < 4; ++ni)
                acc[mi][ni] = __builtin_amdgcn_mfma_f32_16x16x32_bf16(af[mi], bfr[ni], acc[mi][ni], 0, 0, 0);
        __builtin_amdgcn_s_setprio(0);
        // ---- phase 1: ks=0, mi 4-7 (stage A half 1 + W half 0)
        if (pf) { stA(t + 1, nA, 1); stW(t + 1, nW, 0); }
        #pragma unroll
        for (int mi = 0; mi < 4; ++mi) af[mi] = rdA(cA, 0, mi + 4);
        __builtin_amdgcn_s_setprio(1);
        #pragma unroll
        for (int mi = 0; mi < 4; ++mi)
            #pragma unroll
            for (int ni = 0; ni < 4; ++ni)
                acc[mi + 4][ni] = __builtin_amdgcn_mfma_f32_16x16x32_bf16(af[mi], bfr[ni], acc[mi + 4][ni], 0, 0, 0);
        __builtin_amdgcn_s_setprio(0);
        // ---- phase 2: ks=1, mi 0-3 (stage W half 1)
        if (pf) stW(t + 1, nW, 1);
        #pragma unroll
        for (int ni = 0; ni < 4; ++ni) bfr[ni] = rdB(cW, 1, ni);
        #pragma unroll
        for (int mi = 0; mi < 4; ++mi) af[mi] = rdA(cA, 1, mi);
        __builtin_amdgcn_s_setprio(1);
        #pragma unroll
        for (int mi = 0; mi < 4; ++mi)
            #pragma unroll
            for (int ni = 0; ni < 4; ++ni)
                acc[mi][ni] = __builtin_amdgcn_mfma_f32_16x16x32_bf16(af[mi], bfr[ni], acc[mi][ni], 0, 0, 0);
        __builtin_amdgcn_s_setprio(0);
        // ---- phase 3: ks=1, mi 4-7
        #pragma unroll
        for (int mi = 0; mi < 4; ++mi) af[mi] = rdA(cA, 1, mi + 4);
        __builtin_amdgcn_s_setprio(1);
        #pragma unroll
        for (int mi = 0; mi < 4; ++mi)
            #pragma unroll
            for (int ni = 0; ni < 4; ++ni)
                acc[mi + 4][ni] = __builtin_amdgcn_mfma_f32_16x16x32_bf16(af[mi], bfr[ni], acc[mi + 4][ni], 0, 0, 0);
        __builtin_amdgcn_s_setprio(0);
        // ---- tile end: drain t+1's loads (had a full tile of compute to land), barrier
        asm volatile("s_waitcnt vmcnt(0)" ::: "memory");
        __builtin_amdgcn_s_barrier();
    };

    #pragma unroll 1
    for (int tt = 0; tt < 8; ++tt) {
        body(2 * tt,     A0, W0, A1, W1, true);
        body(2 * tt + 1, A1, W1, A0, W0, tt < 7);
    }

    // ---- score epilogue (per-wave side: wc<2 -> a, else -> b) ----
    const float* qsrc = (wc < 2) ? P.qa[br] : P.qb[br];
    const float* vsrc = (wc < 2) ? P.va[br] : P.vb[br];
    float* osrc       = (wc < 2) ? P.oa[br] : P.ob[br];
    const int nbase0 = ((wc < 2) ? na : nb) + (wc & 1) * 64;
    #pragma unroll
    for (int mi = 0; mi < 8; ++mi) {
        int mbase = m0 + wr * 128 + mi * 16;
        int bb = mbase >> bshift;                 // constant across the 16-row fragment
        const float* qrow = qsrc + (size_t)bb * 1024;
        float part[4] = {0.f, 0.f, 0.f, 0.f};
        #pragma unroll
        for (int ni = 0; ni < 4; ++ni) {
            int nn = nbase0 + ni * 16 + lrow;
            float qn = qrow[nn], vn = vsrc[nn];
            #pragma unroll
            for (int r = 0; r < 4; ++r)
                part[r] += fast_tanh(acc[mi][ni][r] + qn) * vn;
        }
        #pragma unroll
        for (int off = 1; off < 16; off <<= 1)
            #pragma unroll
            for (int r = 0; r < 4; ++r)
                part[r] += __shfl_xor(part[r], off, 64);
        if (lrow == 0) {
            #pragma unroll
            for (int r = 0; r < 4; ++r)
                atomicAdd(&osrc[mbase + lk * 4 + r], part[r]);
        }
    }
}

// ============ fused 4-way q-projection: q = x @ W^T + b  (M=128, single-buffered) ============
struct QArgs {
    const ushort* A[4];
    const ushort* W[4];
    const float* bias[4];
    float* out[4];
};

__global__ __launch_bounds__(256, 2) void gemm_q(QArgs Q)
{
    __shared__ char smem[32768];
    char* As = smem;
    char* Ws = smem + 16384;

    const int tid = threadIdx.x;
    const int lane = tid & 63, wv = tid >> 6, wr = wv >> 1, wc = wv & 1;
    const int lrow = lane & 15, lk = lane >> 4;
    const int n0 = blockIdx.y << 7;

    const ushort* A = Q.A[blockIdx.x];
    const ushort* W = Q.W[blockIdx.x];

    f32x4 acc[4][4];
    #pragma unroll
    for (int i = 0; i < 4; ++i)
        #pragma unroll
        for (int j = 0; j < 4; ++j) { f32x4 z = {0.f,0.f,0.f,0.f}; acc[i][j] = z; }

    const int srow = tid >> 3;
    const int g = (tid & 7) ^ (srow & 7);
    const ushort* pA = A + (size_t)srow * 1024 + g * 8;           // m0 = 0
    const ushort* pW = W + (size_t)(n0 + srow) * 1024 + g * 8;

    for (int t = 0; t < 16; ++t) {
        #pragma unroll
        for (int j = 0; j < 4; ++j)
            gload16(pA + (size_t)j * 32768 + (size_t)t * 64, As + j * 4096 + tid * 16);
        #pragma unroll
        for (int j = 0; j < 4; ++j)
            gload16(pW + (size_t)j * 32768 + (size_t)t * 64, Ws + j * 4096 + tid * 16);
        __syncthreads();
        #pragma unroll
        for (int ks = 0; ks < 2; ++ks) {
            bf16x8 af[4], bfr[4];
            const int q = ks * 4 + lk;
            #pragma unroll
            for (int mi = 0; mi < 4; ++mi) {
                int row = wr * 64 + mi * 16 + lrow;
                af[mi] = *(const bf16x8*)(As + row * 128 + ((q ^ (row & 7)) << 4));
            }
            #pragma unroll
            for (int ni = 0; ni < 4; ++ni) {
                int row = wc * 64 + ni * 16 + lrow;
                bfr[ni] = *(const bf16x8*)(Ws + row * 128 + ((q ^ (row & 7)) << 4));
            }
            #pragma unroll
            for (int mi = 0; mi < 4; ++mi)
                #pragma unroll
                for (int ni = 0; ni < 4; ++ni)
                    acc[mi][ni] = __builtin_amdgcn_mfma_f32_16x16x32_bf16(af[mi], bfr[ni], acc[mi][ni], 0, 0, 0);
        }
        __syncthreads();
    }

    float* out = Q.out[blockIdx.x];
    const float* bias = Q.bias[blockIdx.x];
    #pragma unroll
    for (int mi = 0; mi < 4; ++mi) {
        int mrow0 = wr * 64 + mi * 16 + lk * 4;
        #pragma unroll
        for (int ni = 0; ni < 4; ++ni) {
            int n = n0 + wc * 64 + ni * 16 + lrow;
            float bv = bias[n];
            #pragma unroll
            for (int r = 0; r < 4; ++r)
                out[(size_t)(mrow0 + r) * 1024 + n] = acc[mi][ni][r] + bv;
        }
    }
}

// ============ final GEMM (split-K, atomic): out += combined @ W_out^T (+bias at z==0) ============
__global__ __launch_bounds__(256, 2) void gemm_fin(
    const ushort* A, const ushort* W, const float* bias, float* out, int K, int kchunk)
{
    __shared__ char smem[32768];
    char* As = smem;
    char* Ws = smem + 16384;

    const int tid = threadIdx.x;
    const int lane = tid & 63, wv = tid >> 6, wr = wv >> 1, wc = wv & 1;
    const int lrow = lane & 15, lk = lane >> 4;
    const int n0 = blockIdx.y << 7;
    const int nkt = kchunk >> 6;
    const int ktbase = blockIdx.z * nkt;

    f32x4 acc[4][4];
    #pragma unroll
    for (int i = 0; i < 4; ++i)
        #pragma unroll
        for (int j = 0; j < 4; ++j) { f32x4 z = {0.f,0.f,0.f,0.f}; acc[i][j] = z; }

    const int srow = tid >> 3;
    const int g = (tid & 7) ^ (srow & 7);
    const ushort* pA = A + (size_t)srow * K + ktbase * 64 + g * 8;
    const ushort* pW = W + (size_t)(n0 + srow) * K + ktbase * 64 + g * 8;

    for (int t = 0; t < nkt; ++t) {
        #pragma unroll
        for (int j = 0; j < 4; ++j)
            gload16(pA + (size_t)j * 32 * K + (size_t)t * 64, As + j * 4096 + tid * 16);
        #pragma unroll
        for (int j = 0; j < 4; ++j)
            gload16(pW + (size_t)j * 32 * K + (size_t)t * 64, Ws + j * 4096 + tid * 16);
        __syncthreads();
        #pragma unroll
        for (int ks = 0; ks < 2; ++ks) {
            bf16x8 af[4], bfr[4];
            const int q = ks * 4 + lk;
            #pragma unroll
            for (int mi = 0; mi < 4; ++mi) {
                int row = wr * 64 + mi * 16 + lrow;
                af[mi] = *(const bf16x8*)(As + row * 128 + ((q ^ (row & 7)) << 4));
            }
            #pragma unroll
            for (int ni = 0; ni < 4; ++ni) {
                int row = wc * 64 + ni * 16 + lrow;
                bfr[ni] = *(const bf16x8*)(Ws + row * 128 + ((q ^ (row & 7)) << 4));
            }
            #pragma unroll
            for (int mi = 0; mi < 4; ++mi)
                #pragma unroll
                for (int ni = 0; ni < 4; ++ni)
                    acc[mi][ni] = __builtin_amdgcn_mfma_f32_16x16x32_bf16(af[mi], bfr[ni], acc[mi][ni], 0, 0, 0);
        }
        __syncthreads();
    }

    #pragma unroll
    for (int mi = 0; mi < 4; ++mi) {
        int mrow0 = wr * 64 + mi * 16 + lk * 4;
        #pragma unroll
        for (int ni = 0; ni < 4; ++ni) {
            int n = n0 + wc * 64 + ni * 16 + lrow;
            float bv = (blockIdx.z == 0) ? bias[n] : 0.f;
            #pragma unroll
            for (int r = 0; r < 4; ++r)
                atomicAdd(&out[(size_t)(mrow0 + r) * 1024 + n], acc[mi][ni][r] + bv);
        }
    }
}

// ---------------- softmax + context, image branches ----------------
__global__ void softmax_ctx_img(const ushort* __restrict__ iof, const ushort* __restrict__ ipf,
                                const float* __restrict__ sc_io, const float* __restrict__ sc_ip,
                                ushort* __restrict__ combined)
{
    int b = blockIdx.x, br = blockIdx.y;
    const ushort* A  = br ? ipf : iof;
    const float* sc  = br ? sc_ip : sc_io;
    __shared__ float dist[64];
    int tid = threadIdx.x;
    if (tid < 64) {
        float s  = sc[b * 64 + tid];
        float mx = wredmax(s);
        float e  = __expf(s - mx);
        float sm = wredsum(e);
        dist[tid] = e / sm;
    }
    __syncthreads();
    int d0 = tid * 4;
    float a0 = 0, a1 = 0, a2 = 0, a3 = 0;
    const ushort* base = A + (size_t)b * 64 * 1024 + d0;
    #pragma unroll 4
    for (int n = 0; n < 64; ++n) {
        float w = dist[n];
        ushort4 t = *(const ushort4*)(base + (size_t)n * 1024);
        a0 += w * bfu(t.x); a1 += w * bfu(t.y); a2 += w * bfu(t.z); a3 += w * bfu(t.w);
    }
    uint2 o;
    o.x = pack_bf16x2(a0, a1);
    o.y = pack_bf16x2(a2, a3);
    *(uint2*)(combined + (size_t)b * 4096 + br * 1024 + d0) = o;
}

// ---------------- masked softmax + context, text branches ----------------
__global__ void softmax_ctx_text(const ushort* __restrict__ tf,
                                 const float* __restrict__ sc_to, const float* __restrict__ sc_tp,
                                 const float* __restrict__ mask, ushort* __restrict__ combined)
{
    int b = blockIdx.x;
    __shared__ float d3[256], d4[256], red[8];
    int tid = threadIdx.x, lane = tid & 63, wv = tid >> 6;
    float s3 = sc_to[b * 256 + tid], s4 = sc_tp[b * 256 + tid], m = mask[b * 256 + tid];
    float m3 = wredmax(s3), m4 = wredmax(s4);
    if (lane == 0) { red[wv] = m3; red[4 + wv] = m4; }
    __syncthreads();
    m3 = fmaxf(fmaxf(red[0], red[1]), fmaxf(red[2], red[3]));
    m4 = fmaxf(fmaxf(red[4], red[5]), fmaxf(red[6], red[7]));
    float e3 = __expf(s3 - m3) * m, e4 = __expf(s4 - m4) * m;
    float t3 = wredsum(e3), t4 = wredsum(e4);
    __syncthreads();
    if (lane == 0) { red[wv] = t3; red[4 + wv] = t4; }
    __syncthreads();
    t3 = red[0] + red[1] + red[2] + red[3];
    t4 = red[4] + red[5] + red[6] + red[7];
    d3[tid] = e3 / t3; d4[tid] = e4 / t4;
    __syncthreads();
    int d0 = tid * 4;
    float a0 = 0, a1 = 0, a2 = 0, a3 = 0, c0 = 0, c1 = 0, c2 = 0, c3 = 0;
    const ushort* base = tf + (size_t)b * 256 * 1024 + d0;
    #pragma unroll 4
    for (int l = 0; l < 256; ++l) {
        float w3 = d3[l], w4 = d4[l];
        ushort4 t = *(const ushort4*)(base + (size_t)l * 1024);
        float f0 = bfu(t.x), f1 = bfu(t.y), f2 = bfu(t.z), f3 = bfu(t.w);
        a0 += w3 * f0; a1 += w3 * f1; a2 += w3 * f2; a3 += w3 * f3;
        c0 += w4 * f0; c1 += w4 * f1; c2 += w4 * f2; c3 += w4 * f3;
    }
    uint2 o;
    o.x = pack_bf16x2(a0, a1); o.y = pack_bf16x2(a2, a3);
    *(uint2*)(combined + (size_t)b * 4096 + 2048 + d0) = o;
    o.x = pack_bf16x2(c0, c1); o.y = pack_bf16x2(c2, c3);
    *(uint2*)(combined + (size_t)b * 4096 + 3072 + d0) = o;
}

extern "C" void kernel_launch(void* const* d_in, const int* in_sizes, int n_in,
                              void* d_out, int out_size, void* d_ws, size_t ws_size,
                              hipStream_t stream) {
    const float* text_feat        = (const float*)d_in[0];
    const float* text_feats       = (const float*)d_in[1];
    const float* img_object_feat  = (const float*)d_in[2];
    const float* img_object_feats = (const float*)d_in[3];
    const float* img_place_feat   = (const float*)d_in[4];
    const float* img_place_feats  = (const float*)d_in[5];
    const float* src_mask         = (const float*)d_in[6];
    const float* v_to  = (const float*)d_in[7];
    const float* v_tp  = (const float*)d_in[8];
    const float* v_io  = (const float*)d_in[9];
    const float* v_ip  = (const float*)d_in[10];
    const float* Wsrc[9] = {
        (const float*)d_in[11],  // W_t2o
        (const float*)d_in[12],  // W_t2p
        (const float*)d_in[13],  // W_o2t
        (const float*)d_in[14],  // W_p2t
        (const float*)d_in[15],  // W_oo
        (const float*)d_in[17],  // W_pp
        (const float*)d_in[19],  // W_tot
        (const float*)d_in[21],  // W_tpt
        (const float*)d_in[23],  // W_out
    };
    const float* b_oo  = (const float*)d_in[16];
    const float* b_pp  = (const float*)d_in[18];
    const float* b_tot = (const float*)d_in[20];
    const float* b_tpt = (const float*)d_in[22];
    const float* b_out = (const float*)d_in[24];

    // ---- workspace layout ----
    char* p = (char*)d_ws;
    auto alloc = [&](size_t bytes) { char* r = p; p += (bytes + 255) & ~(size_t)255; return r; };
    ushort* wb[9];
    for (int i = 0; i < 8; ++i) wb[i] = (ushort*)alloc((size_t)1024 * 1024 * 2);
    wb[8] = (ushort*)alloc((size_t)1024 * 4096 * 2);
    ushort* tf_bf   = (ushort*)alloc((size_t)32768 * 1024 * 2);
    ushort* iof_bf  = (ushort*)alloc((size_t)8192 * 1024 * 2);
    ushort* ipf_bf  = (ushort*)alloc((size_t)8192 * 1024 * 2);
    ushort* tfq_bf  = (ushort*)alloc((size_t)128 * 1024 * 2);
    ushort* iofq_bf = (ushort*)alloc((size_t)128 * 1024 * 2);
    ushort* ipfq_bf = (ushort*)alloc((size_t)128 * 1024 * 2);
    float* q_tot = (float*)alloc((size_t)128 * 1024 * 4);
    float* q_tpt = (float*)alloc((size_t)128 * 1024 * 4);
    float* q_oo  = (float*)alloc((size_t)128 * 1024 * 4);
    float* q_pp  = (float*)alloc((size_t)128 * 1024 * 4);
    float* scores = (float*)alloc((size_t)(8192 * 2 + 32768 * 2) * 4);
    float* sc_io = scores, *sc_ip = scores + 8192, *sc_to = scores + 16384, *sc_tp = scores + 49152;
    ushort* comb_bf = (ushort*)alloc((size_t)128 * 4096 * 2);

    // ---- 1) batched f32->bf16 conversion ----
    CvtTab tab;
    unsigned n4[15];
    const float* srcs[15];
    ushort* dsts[15];
    for (int i = 0; i < 8; ++i) { srcs[i] = Wsrc[i]; dsts[i] = wb[i]; n4[i] = 262144; }
    srcs[8]  = Wsrc[8];          dsts[8]  = wb[8];   n4[8]  = 1048576;
    srcs[9]  = text_feats;       dsts[9]  = tf_bf;   n4[9]  = 8388608;
    srcs[10] = img_object_feats; dsts[10] = iof_bf;  n4[10] = 2097152;
    srcs[11] = img_place_feats;  dsts[11] = ipf_bf;  n4[11] = 2097152;
    srcs[12] = text_feat;        dsts[12] = tfq_bf;  n4[12] = 32768;
    srcs[13] = img_object_feat;  dsts[13] = iofq_bf; n4[13] = 32768;
    srcs[14] = img_place_feat;   dsts[14] = ipfq_bf; n4[14] = 32768;
    unsigned cum = 0;
    for (int i = 0; i < 15; ++i) {
        tab.src[i] = srcs[i]; tab.dst[i] = dsts[i]; tab.cum[i] = cum; cum += n4[i];
    }
    tab.src[15] = nullptr; tab.dst[15] = nullptr; tab.cum[15] = cum; tab.cum[16] = cum;
    cvt_all<<<4096, 256, 0, stream>>>(tab, cum);

    // ---- 2) zero atomic targets ----
    hipMemsetAsync(scores, 0, (size_t)(8192 * 2 + 32768 * 2) * 4, stream);
    hipMemsetAsync(d_out, 0, (size_t)128 * 1024 * 4, stream);

    // ---- 3) fused q projections ----
    QArgs qa;
    qa.A[0] = tfq_bf;  qa.W[0] = wb[6]; qa.bias[0] = b_tot; qa.out[0] = q_tot;
    qa.A[1] = tfq_bf;  qa.W[1] = wb[7]; qa.bias[1] = b_tpt; qa.out[1] = q_tpt;
    qa.A[2] = iofq_bf; qa.W[2] = wb[4]; qa.bias[2] = b_oo;  qa.out[2] = q_oo;
    qa.A[3] = ipfq_bf; qa.W[3] = wb[5]; qa.bias[3] = b_pp;  qa.out[3] = q_pp;
    gemm_q<<<dim3(4, 8), 256, 0, stream>>>(qa);

    // ---- 4) score GEMMs (deep-pipelined) ----
    // img: branch 0 = object, branch 1 = place; single W per branch, N-tile = (na, na+128)
    PArgs pi;
    pi.A[0] = iof_bf;  pi.Wa[0] = wb[2]; pi.Wb[0] = wb[2];
    pi.qa[0] = q_tot;  pi.qb[0] = q_tot; pi.va[0] = v_to; pi.vb[0] = v_to;
    pi.oa[0] = sc_io;  pi.ob[0] = sc_io;
    pi.A[1] = ipf_bf;  pi.Wa[1] = wb[3]; pi.Wb[1] = wb[3];
    pi.qa[1] = q_tpt;  pi.qb[1] = q_tpt; pi.va[1] = v_tp; pi.vb[1] = v_tp;
    pi.oa[1] = sc_ip;  pi.ob[1] = sc_ip;
    gemm_pipe<<<dim3(64, 4), 512, 131072, stream>>>(pi, 256, 128, 6, 5);

    // text: dual-W (W_t2o | W_t2p) sharing one A pass
    PArgs pt;
    pt.A[0] = tf_bf;   pt.Wa[0] = wb[0]; pt.Wb[0] = wb[1];
    pt.qa[0] = q_oo;   pt.qb[0] = q_pp;  pt.va[0] = v_io; pt.vb[0] = v_ip;
    pt.oa[0] = sc_to;  pt.ob[0] = sc_tp;
    pt.A[1] = pt.A[0]; pt.Wa[1] = pt.Wa[0]; pt.Wb[1] = pt.Wb[0];
    pt.qa[1] = pt.qa[0]; pt.qb[1] = pt.qb[0]; pt.va[1] = pt.va[0]; pt.vb[1] = pt.vb[0];
    pt.oa[1] = pt.oa[0]; pt.ob[1] = pt.ob[0];
    gemm_pipe<<<dim3(128, 8), 512, 131072, stream>>>(pt, 128, 0, 8, 7);

    // ---- 5) softmax + context -> combined (bf16) ----
    softmax_ctx_img<<<dim3(128, 2), 256, 0, stream>>>(iof_bf, ipf_bf, sc_io, sc_ip, comb_bf);
    softmax_ctx_text<<<dim3(128), 256, 0, stream>>>(tf_bf, sc_to, sc_tp, src_mask, comb_bf);

    // ---- 6) out = combined @ W_out^T + b_out (split-K=8, atomic) ----
    gemm_fin<<<dim3(1, 8, 8), 256, 0, stream>>>(comb_bf, wb[8], b_out, (float*)d_out, 4096, 512);
}